// Round 13
// baseline (302.624 us; speedup 1.0000x reference)
//
#include <hip/hip_runtime.h>
#include <hip/hip_bf16.h>
#include <hip/hip_fp16.h>
#include <math.h>

// RWKV-7 Tmix: B=2, T=1024, C=1024, H=16, N=64
constexpr int Bb = 2, Tt = 1024, Cc = 1024, Hh = 16, Nn = 64;
constexpr int Mtot = Bb * Tt;          // 2048 rows
constexpr int PACKW = 6 * Nn;          // 384 floats per (b,h,t)
constexpr int SL_R = 0, SL_W = 1, SL_K = 2, SL_V = 3, SL_NK = 4, SL_BV = 5;
constexpr int PK2S = 768;              // bytes per (b,h,t) in f16 scan pack

typedef _Float16 half8 __attribute__((ext_vector_type(8)));
typedef float f32x4 __attribute__((ext_vector_type(4)));
typedef unsigned int u32x2 __attribute__((ext_vector_type(2)));

__device__ __forceinline__ float sigf(float x) { return 1.f / (1.f + expf(-x)); }

__device__ __forceinline__ unsigned short f2h(float f) {
    _Float16 h = (_Float16)f;
    return __builtin_bit_cast(unsigned short, h);
}
__device__ __forceinline__ float h2lo(unsigned int u) {
    return (float)__builtin_bit_cast(_Float16, (unsigned short)(u & 0xffffu));
}
__device__ __forceinline__ float h2hi(unsigned int u) {
    return (float)__builtin_bit_cast(_Float16, (unsigned short)(u >> 16));
}

// ===========================================================================
// mix + cast to f16: xr,xk,xv,xw,xa,xg  (xf + z*2M), z = 0..5
// ===========================================================================
__global__ __launch_bounds__(256) void mixcast_k(
    const float* __restrict__ x, const float* __restrict__ mr,
    const float* __restrict__ mk, const float* __restrict__ mv,
    const float* __restrict__ mw, const float* __restrict__ ma,
    const float* __restrict__ mg, unsigned short* __restrict__ xf)
{
    int idx = (blockIdx.x * 256 + threadIdx.x) * 4;
    int m = idx >> 10, c = idx & 1023;
    int t = m & (Tt - 1);
    float4 xc = *(const float4*)(x + idx);
    float4 xp = make_float4(0.f, 0.f, 0.f, 0.f);
    if (t) xp = *(const float4*)(x + idx - Cc);
    float4 d = make_float4(xp.x - xc.x, xp.y - xc.y, xp.z - xc.z, xp.w - xc.w);
    float4 m4;
    ushort4 o4;
#define EMIT(mixp, zoff)                                               \
    m4 = *(const float4*)(mixp + c);                                   \
    o4.x = f2h(xc.x + d.x * m4.x); o4.y = f2h(xc.y + d.y * m4.y);      \
    o4.z = f2h(xc.z + d.z * m4.z); o4.w = f2h(xc.w + d.w * m4.w);      \
    *(ushort4*)(xf + (size_t)(zoff)*2097152 + idx) = o4;
    EMIT(mr, 0)
    EMIT(mk, 1)
    EMIT(mv, 2)
    EMIT(mw, 3)
    EMIT(ma, 4)
    EMIT(mg, 5)
#undef EMIT
}

// ===========================================================================
// big weight transpose + cast f16: WT[n][k] from W[k][n]. 64x64 tiles, z=0..3
// ===========================================================================
__global__ __launch_bounds__(256) void wtrans_k(
    const float* __restrict__ W0, const float* __restrict__ W1,
    const float* __restrict__ W2, const float* __restrict__ W3,
    unsigned short* __restrict__ WT)
{
    __shared__ float ls[64][65];
    const int z = blockIdx.z;
    const float* W = (z == 0) ? W0 : (z == 1) ? W1 : (z == 2) ? W2 : W3;
    unsigned short* dst = WT + (size_t)z * Cc * Cc;
    const int k0 = blockIdx.x * 64, n0 = blockIdx.y * 64;
    const int tid = threadIdx.x;
    const int rr = tid >> 4, c4 = tid & 15;
#pragma unroll
    for (int q = 0; q < 4; q++) {
        int kr = rr + q * 16;
        float4 v = *(const float4*)(W + (size_t)(k0 + kr) * Cc + n0 + c4 * 4);
        ls[kr][c4 * 4 + 0] = v.x; ls[kr][c4 * 4 + 1] = v.y;
        ls[kr][c4 * 4 + 2] = v.z; ls[kr][c4 * 4 + 3] = v.w;
    }
    __syncthreads();
#pragma unroll
    for (int q = 0; q < 4; q++) {
        int nr = rr + q * 16;
        ushort4 o;
        o.x = f2h(ls[c4 * 4 + 0][nr]);
        o.y = f2h(ls[c4 * 4 + 1][nr]);
        o.z = f2h(ls[c4 * 4 + 2][nr]);
        o.w = f2h(ls[c4 * 4 + 3][nr]);
        *(ushort4*)(dst + (size_t)(n0 + nr) * Cc + k0 + c4 * 4) = o;
    }
}

// ===========================================================================
// 6 small low-rank weight transposes -> f16, one launch (128 tile-blocks).
// ===========================================================================
__global__ __launch_bounds__(256) void tr6_k(
    const float* __restrict__ w1, const float* __restrict__ a1, const float* __restrict__ g1,
    const float* __restrict__ w2, const float* __restrict__ a2, const float* __restrict__ g2,
    unsigned short* __restrict__ wts)
{
    int t = blockIdx.x;
    const float* src; unsigned short* dst; int R, C, tr, tc;
    if (t < 16)      { src = w1; dst = wts + 0;      R = 1024; C = 64;   tr = t;            tc = 0; }
    else if (t < 32) { src = a1; dst = wts + 65536;  R = 1024; C = 64;   tr = t - 16;       tc = 0; }
    else if (t < 64) { src = g1; dst = wts + 131072; R = 1024; C = 128;  tr = (t - 32) >> 1; tc = (t - 32) & 1; }
    else if (t < 80) { src = w2; dst = wts + 262144; R = 64;   C = 1024; tr = 0;            tc = t - 64; }
    else if (t < 96) { src = a2; dst = wts + 327680; R = 64;   C = 1024; tr = 0;            tc = t - 80; }
    else             { src = g2; dst = wts + 393216; R = 128;  C = 1024; tr = (t - 96) & 1; tc = (t - 96) >> 1; }
    __shared__ float ls[64][65];
    const int tid = threadIdx.x, rr = tid >> 4, c4 = tid & 15;
    const int r0 = tr * 64, c0 = tc * 64;
#pragma unroll
    for (int q = 0; q < 4; q++) {
        int r = rr + q * 16;
        float4 v = *(const float4*)(src + (size_t)(r0 + r) * C + c0 + c4 * 4);
        ls[r][c4 * 4 + 0] = v.x; ls[r][c4 * 4 + 1] = v.y;
        ls[r][c4 * 4 + 2] = v.z; ls[r][c4 * 4 + 3] = v.w;
    }
    __syncthreads();
#pragma unroll
    for (int q = 0; q < 4; q++) {
        int c = rr + q * 16;
        ushort4 o;
        o.x = f2h(ls[c4 * 4 + 0][c]);
        o.y = f2h(ls[c4 * 4 + 1][c]);
        o.z = f2h(ls[c4 * 4 + 2][c]);
        o.w = f2h(ls[c4 * 4 + 3][c]);
        *(ushort4*)(dst + (size_t)(c0 + c) * R + r0 + c4 * 4) = o;
    }
}

// ===========================================================================
// f16 MFMA GEMM: out = A[M,K] @ WT[N,K]^T. 128x64 tile, 4 waves, dbuf LDS.
// ===========================================================================
template <int RKV>
__global__ __launch_bounds__(256) void mgemm_k(
    const unsigned short* __restrict__ Abase, const unsigned short* __restrict__ WT,
    float* __restrict__ out, int M, int Ncol, int K)
{
    __shared__ unsigned short Ash[2][128][40];
    __shared__ unsigned short Bsh[2][64][40];
    const int z = RKV ? blockIdx.z : 0;
    const unsigned short* A = Abase + (size_t)z * 2097152;
    const unsigned short* BT = WT + (size_t)z * 1048576;
    const int tid = threadIdx.x;
    const int lane = tid & 63, wid = tid >> 6;
    const int wr = wid >> 1, wc = wid & 1;
    const int bm = blockIdx.y * 128, bn = blockIdx.x * 64;
    const int l15 = lane & 15, lk = lane >> 4;
    const int srow = tid >> 2, skc = tid & 3;

    f32x4 acc[4][2];
#pragma unroll
    for (int i = 0; i < 4; i++)
#pragma unroll
        for (int j = 0; j < 2; j++) acc[i][j] = (f32x4){0.f, 0.f, 0.f, 0.f};

    uint4 ra0, ra1, rb0;
    const size_t arow = (size_t)(bm + srow) * K + skc * 8;
    const size_t brow = (size_t)(bn + srow) * K + skc * 8;

#define LOADG(k0)                                                  \
    ra0 = *(const uint4*)(A + arow + (k0));                        \
    ra1 = *(const uint4*)(A + arow + (size_t)64 * K + (k0));       \
    rb0 = *(const uint4*)(BT + brow + (k0));
#define WRITEL(buf)                                                \
    *(uint4*)&Ash[buf][srow][skc * 8] = ra0;                       \
    *(uint4*)&Ash[buf][srow + 64][skc * 8] = ra1;                  \
    *(uint4*)&Bsh[buf][srow][skc * 8] = rb0;

    LOADG(0)
    WRITEL(0)
    __syncthreads();

    int cur = 0;
    for (int k0 = 0; k0 < K; k0 += 32) {
        const bool pf = (k0 + 32 < K);
        if (pf) { LOADG(k0 + 32) }
        half8 af[4], bf[2];
#pragma unroll
        for (int m = 0; m < 4; m++)
            af[m] = *(const half8*)&Ash[cur][wr * 64 + m * 16 + l15][lk * 8];
#pragma unroll
        for (int n = 0; n < 2; n++)
            bf[n] = *(const half8*)&Bsh[cur][wc * 32 + n * 16 + l15][lk * 8];
#pragma unroll
        for (int m = 0; m < 4; m++)
#pragma unroll
            for (int n = 0; n < 2; n++)
                acc[m][n] = __builtin_amdgcn_mfma_f32_16x16x32_f16(af[m], bf[n], acc[m][n], 0, 0, 0);
        if (pf) { WRITEL(cur ^ 1) }
        __syncthreads();
        cur ^= 1;
    }
#undef LOADG
#undef WRITEL

    const int slot = (z == 0) ? SL_R : (z == 1) ? SL_K : SL_V;
#pragma unroll
    for (int m = 0; m < 4; m++) {
#pragma unroll
        for (int n = 0; n < 2; n++) {
            int col = bn + wc * 32 + n * 16 + l15;
#pragma unroll
            for (int r = 0; r < 4; r++) {
                int row = bm + wr * 64 + m * 16 + lk * 4 + r;
                float cval = acc[m][n][r];
                if (RKV == 0) {
                    out[(size_t)row * Ncol + col] = cval;
                } else {
                    int b = row >> 10, t = row & (Tt - 1);
                    int h = col >> 6, nn2 = col & 63;
                    out[((size_t)(b * Hh + h) * Tt + t) * PACKW + slot * Nn + nn2] = cval;
                }
            }
        }
    }
}

// ===========================================================================
// low-rank stage 1 (fused w/a/g): h1[2048][256] f16.
// ===========================================================================
__global__ __launch_bounds__(256) void lr1_k(
    const unsigned short* __restrict__ xf, const unsigned short* __restrict__ wts,
    unsigned short* __restrict__ h1)
{
    __shared__ unsigned short Ash[2][128][40];
    __shared__ unsigned short Bsh[2][64][40];
    const int bx = blockIdx.x;
    const unsigned short* A = xf + (size_t)(bx == 0 ? 3 : bx == 1 ? 4 : 5) * 2097152;
    const unsigned short* BT = wts + (bx == 0 ? 0 : bx == 1 ? 65536 : 131072 + (bx - 2) * 65536);
    const int colbase = bx * 64;
    const int K = 1024;
    const int tid = threadIdx.x;
    const int lane = tid & 63, wid = tid >> 6;
    const int wr = wid >> 1, wc = wid & 1;
    const int bm = blockIdx.y * 128;
    const int l15 = lane & 15, lk = lane >> 4;
    const int srow = tid >> 2, skc = tid & 3;

    f32x4 acc[4][2];
#pragma unroll
    for (int i = 0; i < 4; i++)
#pragma unroll
        for (int j = 0; j < 2; j++) acc[i][j] = (f32x4){0.f, 0.f, 0.f, 0.f};

    uint4 ra0, ra1, rb0;
    const size_t arow = (size_t)(bm + srow) * K + skc * 8;
    const size_t brow = (size_t)srow * K + skc * 8;

#define LOADG(k0)                                                  \
    ra0 = *(const uint4*)(A + arow + (k0));                        \
    ra1 = *(const uint4*)(A + arow + (size_t)64 * K + (k0));       \
    rb0 = *(const uint4*)(BT + brow + (k0));
#define WRITEL(buf)                                                \
    *(uint4*)&Ash[buf][srow][skc * 8] = ra0;                       \
    *(uint4*)&Ash[buf][srow + 64][skc * 8] = ra1;                  \
    *(uint4*)&Bsh[buf][srow][skc * 8] = rb0;

    LOADG(0)
    WRITEL(0)
    __syncthreads();

    int cur = 0;
    for (int k0 = 0; k0 < K; k0 += 32) {
        const bool pf = (k0 + 32 < K);
        if (pf) { LOADG(k0 + 32) }
        half8 af[4], bf[2];
#pragma unroll
        for (int m = 0; m < 4; m++)
            af[m] = *(const half8*)&Ash[cur][wr * 64 + m * 16 + l15][lk * 8];
#pragma unroll
        for (int n = 0; n < 2; n++)
            bf[n] = *(const half8*)&Bsh[cur][wc * 32 + n * 16 + l15][lk * 8];
#pragma unroll
        for (int m = 0; m < 4; m++)
#pragma unroll
            for (int n = 0; n < 2; n++)
                acc[m][n] = __builtin_amdgcn_mfma_f32_16x16x32_f16(af[m], bf[n], acc[m][n], 0, 0, 0);
        if (pf) { WRITEL(cur ^ 1) }
        __syncthreads();
        cur ^= 1;
    }
#undef LOADG
#undef WRITEL

#pragma unroll
    for (int m = 0; m < 4; m++) {
#pragma unroll
        for (int n = 0; n < 2; n++) {
            int col = colbase + wc * 32 + n * 16 + l15;
#pragma unroll
            for (int r = 0; r < 4; r++) {
                int row = bm + wr * 64 + m * 16 + lk * 4 + r;
                float c = acc[m][n][r];
                if (bx == 0) c = tanhf(c);
                else if (bx >= 2) c = sigf(c);
                h1[(size_t)row * 256 + col] = f2h(c);
            }
        }
    }
}

// ===========================================================================
// low-rank stage 2: grid (16,16,3): z=0 -> SL_W decay, z=1 -> SL_BV sigmoid a,
// z=2 -> gbuf
// ===========================================================================
__global__ __launch_bounds__(256) void lr2_k(
    const unsigned short* __restrict__ h1, const unsigned short* __restrict__ wts,
    const float* __restrict__ w0, const float* __restrict__ a0,
    float* __restrict__ pack, float* __restrict__ gbuf)
{
    __shared__ unsigned short Ash[128][40];
    __shared__ unsigned short Bsh[64][40];
    const int z = blockIdx.z;
    const int K = (z == 2) ? 128 : 64;
    const int aoff = (z == 0) ? 0 : (z == 1) ? 64 : 128;
    const unsigned short* BT = wts + 262144 + z * 65536;
    const int tid = threadIdx.x;
    const int lane = tid & 63, wid = tid >> 6;
    const int wr = wid >> 1, wc = wid & 1;
    const int bm = blockIdx.y * 128, bn = blockIdx.x * 64;
    const int l15 = lane & 15, lk = lane >> 4;
    const int srow = tid >> 2, skc = tid & 3;

    f32x4 acc[4][2];
#pragma unroll
    for (int i = 0; i < 4; i++)
#pragma unroll
        for (int j = 0; j < 2; j++) acc[i][j] = (f32x4){0.f, 0.f, 0.f, 0.f};

    for (int k0 = 0; k0 < K; k0 += 32) {
        uint4 ra0 = *(const uint4*)(h1 + (size_t)(bm + srow) * 256 + aoff + k0 + skc * 8);
        uint4 ra1 = *(const uint4*)(h1 + (size_t)(bm + srow + 64) * 256 + aoff + k0 + skc * 8);
        uint4 rb0 = *(const uint4*)(BT + (size_t)(bn + srow) * K + k0 + skc * 8);
        *(uint4*)&Ash[srow][skc * 8] = ra0;
        *(uint4*)&Ash[srow + 64][skc * 8] = ra1;
        *(uint4*)&Bsh[srow][skc * 8] = rb0;
        __syncthreads();
        half8 af[4], bf[2];
#pragma unroll
        for (int m = 0; m < 4; m++)
            af[m] = *(const half8*)&Ash[wr * 64 + m * 16 + l15][lk * 8];
#pragma unroll
        for (int n = 0; n < 2; n++)
            bf[n] = *(const half8*)&Bsh[wc * 32 + n * 16 + l15][lk * 8];
#pragma unroll
        for (int m = 0; m < 4; m++)
#pragma unroll
            for (int n = 0; n < 2; n++)
                acc[m][n] = __builtin_amdgcn_mfma_f32_16x16x32_f16(af[m], bf[n], acc[m][n], 0, 0, 0);
        __syncthreads();
    }

#pragma unroll
    for (int m = 0; m < 4; m++) {
#pragma unroll
        for (int n = 0; n < 2; n++) {
            int col = bn + wc * 32 + n * 16 + l15;
#pragma unroll
            for (int r = 0; r < 4; r++) {
                int row = bm + wr * 64 + m * 16 + lk * 4 + r;
                float c = acc[m][n][r];
                int b = row >> 10, t = row & (Tt - 1);
                int h = col >> 6, nn2 = col & 63;
                if (z == 0) {
                    pack[((size_t)(b * Hh + h) * Tt + t) * PACKW + SL_W * Nn + nn2] = expf(-expf(w0[col] + c));
                } else if (z == 1) {
                    pack[((size_t)(b * Hh + h) * Tt + t) * PACKW + SL_BV * Nn + nn2] = sigf(a0[col] + c);
                } else {
                    gbuf[(size_t)row * Cc + col] = c;
                }
            }
        }
    }
}

// ===========================================================================
// prep: kk normalize; writes kmod to pack (for post) + f16 scan pack pk2 v2.
// pk2 per (bh,t), stride 768B:
//   [0,256):   qa[64] u32: r|k per col
//   [256,512): qb[64] u32: -kk|kk*a per col
//   [512,640): w[64] f16
//   [640,768): v[64] f16
// ===========================================================================
__global__ __launch_bounds__(256) void prep_k(float* __restrict__ pk,
                                              unsigned char* __restrict__ pk2,
                                              const float* __restrict__ k_k,
                                              const float* __restrict__ k_a)
{
    int inst = blockIdx.x * 4 + (threadIdx.x >> 6);
    int lane = threadIdx.x & 63;
    int b = inst >> 14;
    int rem = inst & 16383;
    int t = rem >> 4;
    int h = rem & 15;
    size_t base = ((size_t)(b * Hh + h) * Tt + t) * PACKW;
    int c = h * 64 + lane;
    float rv   = pk[base + SL_R * 64 + lane];
    float wv   = pk[base + SL_W * 64 + lane];
    float kraw = pk[base + SL_K * 64 + lane];
    float vv   = pk[base + SL_V * 64 + lane];
    float a    = pk[base + SL_BV * 64 + lane];
    float kkv = kraw * k_k[c];
    float ss = kkv * kkv;
#pragma unroll
    for (int m = 1; m < 64; m <<= 1) ss += __shfl_xor(ss, m);
    float kkn = kkv / fmaxf(sqrtf(ss), 1e-12f);
    float kmod = kraw * (1.f + (a - 1.f) * k_a[c]);
    pk[base + SL_K * 64 + lane] = kmod;

    unsigned char* sb = pk2 + ((size_t)(b * Hh + h) * Tt + t) * PK2S;
    *(unsigned int*)(sb + lane * 4)       = (unsigned)f2h(rv) | ((unsigned)f2h(kmod) << 16);
    *(unsigned int*)(sb + 256 + lane * 4) = (unsigned)f2h(-kkn) | ((unsigned)f2h(kkn * a) << 16);
    *(unsigned short*)(sb + 512 + lane * 2) = f2h(wv);
    *(unsigned short*)(sb + 640 + lane * 2) = f2h(vv);
}

// ===========================================================================
// WKV scan v11: 1024 one-wave blocks (4/CU), 2 rows/wave (32 lanes/row,
// 2 cols/lane). Slot = 6 VGPRs -> 8-deep ring = 48 regs, FITS the RA's
// demonstrated 56-reg grant (no spill -> counted vmcnt clean). Reduction =
// 4 DPP + ds_swizzle(xor16). Same R12 skeleton otherwise.
// ===========================================================================
template <int C>
__device__ __forceinline__ float dppmov(float x) {
    return __int_as_float(__builtin_amdgcn_mov_dpp(__float_as_int(x), C, 0xF, 0xF, 1));
}
__device__ __forceinline__ float red32(float v) {
    v += dppmov<0xB1>(v);   // quad_perm xor1
    v += dppmov<0x4E>(v);   // quad_perm xor2
    v += dppmov<0x141>(v);  // row_half_mirror (sum over 8)
    v += dppmov<0x140>(v);  // row_mirror (sum over 16)
    v += __int_as_float(__builtin_amdgcn_ds_swizzle(__float_as_int(v), 0x401F)); // xor16
    return v;
}

struct Slot { u32x2 a; u32x2 b; unsigned int w; unsigned int v; };

__device__ __forceinline__ void stepv(float& S0, float& S1, const Slot& f, int jb, float* optr)
{
    float r0 = h2lo(f.a[0]), k0 = h2hi(f.a[0]);
    float r1 = h2lo(f.a[1]), k1 = h2hi(f.a[1]);
    float n0 = h2lo(f.b[0]), b0 = h2hi(f.b[0]);
    float n1 = h2lo(f.b[1]), b1 = h2hi(f.b[1]);
    float w0 = h2lo(f.w), w1 = h2hi(f.w);
    float vv = h2lo(f.v);
    float sa = fmaf(S1, n1, S0 * n0);
    sa = red32(sa);
    S0 = fmaf(S0, w0, fmaf(sa, b0, vv * k0));
    S1 = fmaf(S1, w1, fmaf(sa, b1, vv * k1));
    float ot = fmaf(S1, r1, S0 * r0);
    ot = red32(ot);
    if (jb == 0) *optr = ot;
}

__global__ __launch_bounds__(64, 1) void wkv_k(const unsigned char* __restrict__ pk2,
                                               float* __restrict__ o)
{
    const int bx = blockIdx.x;           // 0..1023
    const int xcd = bx & 7;
    const int ix = bx >> 3;              // 0..127
    const int bh = xcd * 4 + (ix >> 5);  // 32 row-pair waves of a bh share one XCD
    const int rg = ix & 31;
    const int lane = threadIdx.x;
    const int ri = lane >> 5;            // which of the 2 rows
    const int jb = lane & 31;            // col-pair index
    const int i = rg * 2 + ri;           // row
    const int b = bh >> 4, h = bh & 15;
    const unsigned char* base = pk2 + (size_t)bh * Tt * PK2S;
    const unsigned char* p1 = base + jb * 8;         // qa (2 cols); qb at +256 imm
    const unsigned char* p2 = base + 512 + jb * 4;   // w pair
    const unsigned char* p3 = base + 640 + i * 2;    // v[row]
    float* ob = o + (size_t)b * Tt * Cc + h * 64 + i;

    Slot sl[8];

#define ISSUE(s, Q1, Q2, Q3)                                                                              \
    asm volatile("global_load_dwordx2 %0, %1, off"            : "=v"(sl[s].a) : "v"(Q1) : "memory");      \
    asm volatile("global_load_dwordx2 %0, %1, off offset:256" : "=v"(sl[s].b) : "v"(Q1) : "memory");      \
    asm volatile("global_load_dword %0, %1, off"              : "=v"(sl[s].w) : "v"(Q2) : "memory");      \
    asm volatile("global_load_ushort %0, %1, off"             : "=v"(sl[s].v) : "v"(Q3) : "memory");

    // prologue: slots 0..7 <- steps 0..7 (32 loads in flight)
    ISSUE(0, p1 + 0 * PK2S, p2 + 0 * PK2S, p3 + 0 * PK2S)
    ISSUE(1, p1 + 1 * PK2S, p2 + 1 * PK2S, p3 + 1 * PK2S)
    ISSUE(2, p1 + 2 * PK2S, p2 + 2 * PK2S, p3 + 2 * PK2S)
    ISSUE(3, p1 + 3 * PK2S, p2 + 3 * PK2S, p3 + 3 * PK2S)
    ISSUE(4, p1 + 4 * PK2S, p2 + 4 * PK2S, p3 + 4 * PK2S)
    ISSUE(5, p1 + 5 * PK2S, p2 + 5 * PK2S, p3 + 5 * PK2S)
    ISSUE(6, p1 + 6 * PK2S, p2 + 6 * PK2S, p3 + 6 * PK2S)
    ISSUE(7, p1 + 7 * PK2S, p2 + 7 * PK2S, p3 + 7 * PK2S)

    const unsigned char* q1 = p1 + 8 * PK2S;
    const unsigned char* q2 = p2 + 8 * PK2S;
    const unsigned char* q3 = p3 + 8 * PK2S;
    float S0 = 0.f, S1 = 0.f;

#define STEP(u)                                                          \
    asm volatile("s_waitcnt vmcnt(28)" ::: "memory");                    \
    __builtin_amdgcn_sched_barrier(0);                                   \
    stepv(S0, S1, sl[u], jb, ob + (size_t)(t0 + (u)) * Cc);              \
    ISSUE(u, q1, q2, q3)                                                 \
    if (t0 + (u) + 9 < Tt) { q1 += PK2S; q2 += PK2S; q3 += PK2S; }

    for (int t0 = 0; t0 < Tt; t0 += 8) {
        STEP(0) STEP(1) STEP(2) STEP(3) STEP(4) STEP(5) STEP(6) STEP(7)
    }
#undef STEP
#undef ISSUE
}

// ===========================================================================
// post: GroupNorm + rkv + rosa gate + *g -> f16 activation
// ===========================================================================
__global__ __launch_bounds__(256) void post_k(
    const float* __restrict__ o, const float* __restrict__ pk, const float* __restrict__ gbuf,
    const float* __restrict__ r_k, const float* __restrict__ ln_w, const float* __restrict__ ln_b,
    const int* __restrict__ ids, const float* __restrict__ emb, const float* __restrict__ rgate,
    unsigned short* __restrict__ outh)
{
    __shared__ float sred[4];
    const int bt = blockIdx.x;
    const int b = bt >> 10, t = bt & 1023;
    const int tid = threadIdx.x;
    const int c0 = tid * 4;
    const int h = tid >> 4;
    const int nn = c0 & 63;

    float4 o4 = *(const float4*)(o + (size_t)bt * Cc + c0);
    float s = o4.x + o4.y + o4.z + o4.w;
    float ss = o4.x * o4.x + o4.y * o4.y + o4.z * o4.z + o4.w * o4.w;
#pragma unroll
    for (int m = 1; m < 16; m <<= 1) { s += __shfl_xor(s, m); ss += __shfl_xor(ss, m); }
    float mu = s * (1.f / 64.f);
    float inv = rsqrtf(ss * (1.f / 64.f) - mu * mu + 0.00064f);

    size_t pbase = ((size_t)(b * Hh + h) * Tt + t) * PACKW;
    float4 r4 = *(const float4*)(pk + pbase + SL_R * 64 + nn);
    float4 k4 = *(const float4*)(pk + pbase + SL_K * 64 + nn);
    float4 v4 = *(const float4*)(pk + pbase + SL_V * 64 + nn);
    float4 q4 = *(const float4*)(r_k + h * 64 + nn);
    float dot = r4.x * k4.x * q4.x + r4.y * k4.y * q4.y + r4.z * k4.z * q4.z + r4.w * k4.w * q4.w;
#pragma unroll
    for (int m = 1; m < 16; m <<= 1) dot += __shfl_xor(dot, m);

    float4 lw = *(const float4*)(ln_w + c0);
    float4 lb = *(const float4*)(ln_b + c0);
    float e0 = (o4.x - mu) * inv * lw.x + lb.x + dot * v4.x;
    float e1 = (o4.y - mu) * inv * lw.y + lb.y + dot * v4.y;
    float e2 = (o4.z - mu) * inv * lw.z + lb.z + dot * v4.z;
    float e3 = (o4.w - mu) * inv * lw.w + lb.w + dot * v4.w;

    float4 rg4 = *(const float4*)(rgate + c0);
    float gp = sigf(e0 * rg4.x) + sigf(e1 * rg4.y) + sigf(e2 * rg4.z) + sigf(e3 * rg4.w);
#pragma unroll
    for (int m = 1; m < 64; m <<= 1) gp += __shfl_xor(gp, m);
    if ((tid & 63) == 0) sred[tid >> 6] = gp;
    __syncthreads();
    float gate = (sred[0] + sred[1] + sred[2] + sred[3]) * (1.f / 1024.f);

    const int id = ids[bt];
    float4 em = *(const float4*)(emb + (size_t)id * Cc + c0);
    float4 g4 = *(const float4*)(gbuf + (size_t)bt * Cc + c0);
    ushort4 h4;
    h4.x = f2h((e0 * (1.f - gate) + em.x * gate) * g4.x);
    h4.y = f2h((e1 * (1.f - gate) + em.y * gate) * g4.y);
    h4.z = f2h((e2 * (1.f - gate) + em.z * gate) * g4.z);
    h4.w = f2h((e3 * (1.f - gate) + em.w * gate) * g4.w);
    *(ushort4*)(outh + (size_t)bt * Cc + c0) = h4;
}

// ===========================================================================
extern "C" void kernel_launch(void* const* d_in, const int* in_sizes, int n_in,
                              void* d_out, int out_size, void* d_ws, size_t ws_size,
                              hipStream_t stream)
{
    (void)in_sizes; (void)n_in; (void)out_size; (void)ws_size;
    const float* x    = (const float*)d_in[0];
    const int*   ids  = (const int*)d_in[1];
    const float* x_r  = (const float*)d_in[2];
    const float* x_w  = (const float*)d_in[3];
    const float* x_k  = (const float*)d_in[4];
    const float* x_v  = (const float*)d_in[5];
    const float* x_a  = (const float*)d_in[6];
    const float* x_g  = (const float*)d_in[7];
    const float* w0   = (const float*)d_in[8];
    const float* a0   = (const float*)d_in[9];
    const float* w1   = (const float*)d_in[11];
    const float* w2   = (const float*)d_in[12];
    const float* a1   = (const float*)d_in[13];
    const float* a2   = (const float*)d_in[14];
    const float* g1   = (const float*)d_in[17];
    const float* g2   = (const float*)d_in[18];
    const float* k_k  = (const float*)d_in[19];
    const float* k_a  = (const float*)d_in[20];
    const float* r_k  = (const float*)d_in[21];
    const float* Wr   = (const float*)d_in[22];
    const float* Wk   = (const float*)d_in[23];
    const float* Wv   = (const float*)d_in[24];
    const float* Wo   = (const float*)d_in[25];
    const float* ln_w = (const float*)d_in[26];
    const float* ln_b = (const float*)d_in[27];
    const float* emb  = (const float*)d_in[28];
    const float* rg   = (const float*)d_in[29];

    float* ws = (float*)d_ws;
    float* pack = ws;                                          // 12,582,912 f
    float* obuf = pack + (size_t)12582912;                     // 2,097,152 f
    float* gbuf = obuf + (size_t)2097152;                      // 2,097,152 f
    unsigned short* xf  = (unsigned short*)(gbuf + (size_t)2097152);  // 6 x 2,097,152 u16
    unsigned short* wt  = xf + (size_t)6 * 2097152;            // 4 x 1,048,576 u16
    unsigned short* wts = wt + (size_t)4 * 1048576;            // 524,288 u16
    unsigned short* h1  = wts + (size_t)524288;                // 524,288 u16
    unsigned short* obh = xf;   // final activation aliases xr (dead after R proj)
    // pk2 (25,165,824 B) aliases xk..xg + WrT + WkT -- all dead before prep_k.
    unsigned char*  pk2 = (unsigned char*)(xf + (size_t)2097152);

    dim3 blk(256);

    wtrans_k<<<dim3(16, 16, 4), blk, 0, stream>>>(Wr, Wk, Wv, Wo, wt);
    tr6_k<<<dim3(128), blk, 0, stream>>>(w1, a1, g1, w2, a2, g2, wts);
    mixcast_k<<<dim3(2048), blk, 0, stream>>>(x, x_r, x_k, x_v, x_w, x_a, x_g, xf);

    // r, k, v projections (merged z) -> pack slots
    mgemm_k<1><<<dim3(Cc / 64, Mtot / 128, 3), blk, 0, stream>>>(xf, wt, pack, Mtot, Cc, Cc);
    // low-rank chains
    lr1_k<<<dim3(4, 16), blk, 0, stream>>>(xf, wts, h1);
    lr2_k<<<dim3(16, 16, 3), blk, 0, stream>>>(h1, wts, w0, a0, pack, gbuf);

    prep_k<<<dim3(Bb * Tt * Hh / 4), blk, 0, stream>>>(pack, pk2, k_k, k_a);
    wkv_k<<<dim3(1024), dim3(64), 0, stream>>>(pk2, obuf);
    post_k<<<dim3(Mtot), blk, 0, stream>>>(obuf, pack, gbuf, r_k, ln_w, ln_b, ids, emb, rg, obh);
    mgemm_k<0><<<dim3(Cc / 64, Mtot / 128, 1), blk, 0, stream>>>(obh, wt + (size_t)3 * 1048576, (float*)d_out, Mtot, Cc, Cc);
}

// Round 14
// 233.447 us; speedup vs baseline: 1.2963x; 1.2963x over previous
//
#include <hip/hip_runtime.h>
#include <hip/hip_bf16.h>
#include <hip/hip_fp16.h>
#include <math.h>

// RWKV-7 Tmix: B=2, T=1024, C=1024, H=16, N=64
constexpr int Bb = 2, Tt = 1024, Cc = 1024, Hh = 16, Nn = 64;
constexpr int Mtot = Bb * Tt;          // 2048 rows
constexpr int PACKW = 6 * Nn;          // 384 floats per (b,h,t)
constexpr int SL_R = 0, SL_W = 1, SL_K = 2, SL_V = 3, SL_NK = 4, SL_BV = 5;

typedef _Float16 half8 __attribute__((ext_vector_type(8)));
typedef float f32x4 __attribute__((ext_vector_type(4)));

__device__ __forceinline__ float sigf(float x) { return 1.f / (1.f + expf(-x)); }

__device__ __forceinline__ unsigned short f2h(float f) {
    _Float16 h = (_Float16)f;
    return __builtin_bit_cast(unsigned short, h);
}

// ===========================================================================
// mix + cast to f16: xr,xk,xv,xw,xa,xg  (xf + z*2M), z = 0..5
// ===========================================================================
__global__ __launch_bounds__(256) void mixcast_k(
    const float* __restrict__ x, const float* __restrict__ mr,
    const float* __restrict__ mk, const float* __restrict__ mv,
    const float* __restrict__ mw, const float* __restrict__ ma,
    const float* __restrict__ mg, unsigned short* __restrict__ xf)
{
    int idx = (blockIdx.x * 256 + threadIdx.x) * 4;
    int m = idx >> 10, c = idx & 1023;
    int t = m & (Tt - 1);
    float4 xc = *(const float4*)(x + idx);
    float4 xp = make_float4(0.f, 0.f, 0.f, 0.f);
    if (t) xp = *(const float4*)(x + idx - Cc);
    float4 d = make_float4(xp.x - xc.x, xp.y - xc.y, xp.z - xc.z, xp.w - xc.w);
    float4 m4;
    ushort4 o4;
#define EMIT(mixp, zoff)                                               \
    m4 = *(const float4*)(mixp + c);                                   \
    o4.x = f2h(xc.x + d.x * m4.x); o4.y = f2h(xc.y + d.y * m4.y);      \
    o4.z = f2h(xc.z + d.z * m4.z); o4.w = f2h(xc.w + d.w * m4.w);      \
    *(ushort4*)(xf + (size_t)(zoff)*2097152 + idx) = o4;
    EMIT(mr, 0)
    EMIT(mk, 1)
    EMIT(mv, 2)
    EMIT(mw, 3)
    EMIT(ma, 4)
    EMIT(mg, 5)
#undef EMIT
}

// ===========================================================================
// big weight transpose + cast f16: WT[n][k] from W[k][n]. 64x64 tiles, z=0..3
// ===========================================================================
__global__ __launch_bounds__(256) void wtrans_k(
    const float* __restrict__ W0, const float* __restrict__ W1,
    const float* __restrict__ W2, const float* __restrict__ W3,
    unsigned short* __restrict__ WT)
{
    __shared__ float ls[64][65];
    const int z = blockIdx.z;
    const float* W = (z == 0) ? W0 : (z == 1) ? W1 : (z == 2) ? W2 : W3;
    unsigned short* dst = WT + (size_t)z * Cc * Cc;
    const int k0 = blockIdx.x * 64, n0 = blockIdx.y * 64;
    const int tid = threadIdx.x;
    const int rr = tid >> 4, c4 = tid & 15;
#pragma unroll
    for (int q = 0; q < 4; q++) {
        int kr = rr + q * 16;
        float4 v = *(const float4*)(W + (size_t)(k0 + kr) * Cc + n0 + c4 * 4);
        ls[kr][c4 * 4 + 0] = v.x; ls[kr][c4 * 4 + 1] = v.y;
        ls[kr][c4 * 4 + 2] = v.z; ls[kr][c4 * 4 + 3] = v.w;
    }
    __syncthreads();
#pragma unroll
    for (int q = 0; q < 4; q++) {
        int nr = rr + q * 16;
        ushort4 o;
        o.x = f2h(ls[c4 * 4 + 0][nr]);
        o.y = f2h(ls[c4 * 4 + 1][nr]);
        o.z = f2h(ls[c4 * 4 + 2][nr]);
        o.w = f2h(ls[c4 * 4 + 3][nr]);
        *(ushort4*)(dst + (size_t)(n0 + nr) * Cc + k0 + c4 * 4) = o;
    }
}

// ===========================================================================
// 6 small low-rank weight transposes -> f16, one launch (128 tile-blocks).
// wts layout (ushort elems): w1T@0 [64][1024], a1T@65536, g1T@131072 [128][1024],
//                            w2T@262144 [1024][64], a2T@327680, g2T@393216 [1024][128]
// ===========================================================================
__global__ __launch_bounds__(256) void tr6_k(
    const float* __restrict__ w1, const float* __restrict__ a1, const float* __restrict__ g1,
    const float* __restrict__ w2, const float* __restrict__ a2, const float* __restrict__ g2,
    unsigned short* __restrict__ wts)
{
    int t = blockIdx.x;
    const float* src; unsigned short* dst; int R, C, tr, tc;
    if (t < 16)      { src = w1; dst = wts + 0;      R = 1024; C = 64;   tr = t;            tc = 0; }
    else if (t < 32) { src = a1; dst = wts + 65536;  R = 1024; C = 64;   tr = t - 16;       tc = 0; }
    else if (t < 64) { src = g1; dst = wts + 131072; R = 1024; C = 128;  tr = (t - 32) >> 1; tc = (t - 32) & 1; }
    else if (t < 80) { src = w2; dst = wts + 262144; R = 64;   C = 1024; tr = 0;            tc = t - 64; }
    else if (t < 96) { src = a2; dst = wts + 327680; R = 64;   C = 1024; tr = 0;            tc = t - 80; }
    else             { src = g2; dst = wts + 393216; R = 128;  C = 1024; tr = (t - 96) & 1; tc = (t - 96) >> 1; }
    __shared__ float ls[64][65];
    const int tid = threadIdx.x, rr = tid >> 4, c4 = tid & 15;
    const int r0 = tr * 64, c0 = tc * 64;
#pragma unroll
    for (int q = 0; q < 4; q++) {
        int r = rr + q * 16;
        float4 v = *(const float4*)(src + (size_t)(r0 + r) * C + c0 + c4 * 4);
        ls[r][c4 * 4 + 0] = v.x; ls[r][c4 * 4 + 1] = v.y;
        ls[r][c4 * 4 + 2] = v.z; ls[r][c4 * 4 + 3] = v.w;
    }
    __syncthreads();
#pragma unroll
    for (int q = 0; q < 4; q++) {
        int c = rr + q * 16;
        ushort4 o;
        o.x = f2h(ls[c4 * 4 + 0][c]);
        o.y = f2h(ls[c4 * 4 + 1][c]);
        o.z = f2h(ls[c4 * 4 + 2][c]);
        o.w = f2h(ls[c4 * 4 + 3][c]);
        *(ushort4*)(dst + (size_t)(c0 + c) * R + r0 + c4 * 4) = o;
    }
}

// ===========================================================================
// f16 MFMA GEMM: out = A[M,K] @ WT[N,K]^T. 128x64 tile, 4 waves, dbuf LDS.
// RKV==1: z in {0,1,2} picks (xr,xk,xv) + pack slot scatter; RKV==0: f32 out.
// ===========================================================================
template <int RKV>
__global__ __launch_bounds__(256) void mgemm_k(
    const unsigned short* __restrict__ Abase, const unsigned short* __restrict__ WT,
    float* __restrict__ out, int M, int Ncol, int K)
{
    __shared__ unsigned short Ash[2][128][40];
    __shared__ unsigned short Bsh[2][64][40];
    const int z = RKV ? blockIdx.z : 0;
    const unsigned short* A = Abase + (size_t)z * 2097152;
    const unsigned short* BT = WT + (size_t)z * 1048576;
    const int tid = threadIdx.x;
    const int lane = tid & 63, wid = tid >> 6;
    const int wr = wid >> 1, wc = wid & 1;
    const int bm = blockIdx.y * 128, bn = blockIdx.x * 64;
    const int l15 = lane & 15, lk = lane >> 4;
    const int srow = tid >> 2, skc = tid & 3;

    f32x4 acc[4][2];
#pragma unroll
    for (int i = 0; i < 4; i++)
#pragma unroll
        for (int j = 0; j < 2; j++) acc[i][j] = (f32x4){0.f, 0.f, 0.f, 0.f};

    uint4 ra0, ra1, rb0;
    const size_t arow = (size_t)(bm + srow) * K + skc * 8;
    const size_t brow = (size_t)(bn + srow) * K + skc * 8;

#define LOADG(k0)                                                  \
    ra0 = *(const uint4*)(A + arow + (k0));                        \
    ra1 = *(const uint4*)(A + arow + (size_t)64 * K + (k0));       \
    rb0 = *(const uint4*)(BT + brow + (k0));
#define WRITEL(buf)                                                \
    *(uint4*)&Ash[buf][srow][skc * 8] = ra0;                       \
    *(uint4*)&Ash[buf][srow + 64][skc * 8] = ra1;                  \
    *(uint4*)&Bsh[buf][srow][skc * 8] = rb0;

    LOADG(0)
    WRITEL(0)
    __syncthreads();

    int cur = 0;
    for (int k0 = 0; k0 < K; k0 += 32) {
        const bool pf = (k0 + 32 < K);
        if (pf) { LOADG(k0 + 32) }
        half8 af[4], bf[2];
#pragma unroll
        for (int m = 0; m < 4; m++)
            af[m] = *(const half8*)&Ash[cur][wr * 64 + m * 16 + l15][lk * 8];
#pragma unroll
        for (int n = 0; n < 2; n++)
            bf[n] = *(const half8*)&Bsh[cur][wc * 32 + n * 16 + l15][lk * 8];
#pragma unroll
        for (int m = 0; m < 4; m++)
#pragma unroll
            for (int n = 0; n < 2; n++)
                acc[m][n] = __builtin_amdgcn_mfma_f32_16x16x32_f16(af[m], bf[n], acc[m][n], 0, 0, 0);
        if (pf) { WRITEL(cur ^ 1) }
        __syncthreads();
        cur ^= 1;
    }
#undef LOADG
#undef WRITEL

    const int slot = (z == 0) ? SL_R : (z == 1) ? SL_K : SL_V;
#pragma unroll
    for (int m = 0; m < 4; m++) {
#pragma unroll
        for (int n = 0; n < 2; n++) {
            int col = bn + wc * 32 + n * 16 + l15;
#pragma unroll
            for (int r = 0; r < 4; r++) {
                int row = bm + wr * 64 + m * 16 + lk * 4 + r;
                float cval = acc[m][n][r];
                if (RKV == 0) {
                    out[(size_t)row * Ncol + col] = cval;
                } else {
                    int b = row >> 10, t = row & (Tt - 1);
                    int h = col >> 6, nn2 = col & 63;
                    out[((size_t)(b * Hh + h) * Tt + t) * PACKW + slot * Nn + nn2] = cval;
                }
            }
        }
    }
}

// ===========================================================================
// low-rank stage 1 (fused w/a/g): h1[2048][256] f16.
// grid (4,16): bx=0 -> tanh(xw@w1), bx=1 -> xa@a1, bx=2,3 -> sigmoid(xg@g1)
// ===========================================================================
__global__ __launch_bounds__(256) void lr1_k(
    const unsigned short* __restrict__ xf, const unsigned short* __restrict__ wts,
    unsigned short* __restrict__ h1)
{
    __shared__ unsigned short Ash[2][128][40];
    __shared__ unsigned short Bsh[2][64][40];
    const int bx = blockIdx.x;
    const unsigned short* A = xf + (size_t)(bx == 0 ? 3 : bx == 1 ? 4 : 5) * 2097152;
    const unsigned short* BT = wts + (bx == 0 ? 0 : bx == 1 ? 65536 : 131072 + (bx - 2) * 65536);
    const int colbase = bx * 64;
    const int K = 1024;
    const int tid = threadIdx.x;
    const int lane = tid & 63, wid = tid >> 6;
    const int wr = wid >> 1, wc = wid & 1;
    const int bm = blockIdx.y * 128;
    const int l15 = lane & 15, lk = lane >> 4;
    const int srow = tid >> 2, skc = tid & 3;

    f32x4 acc[4][2];
#pragma unroll
    for (int i = 0; i < 4; i++)
#pragma unroll
        for (int j = 0; j < 2; j++) acc[i][j] = (f32x4){0.f, 0.f, 0.f, 0.f};

    uint4 ra0, ra1, rb0;
    const size_t arow = (size_t)(bm + srow) * K + skc * 8;
    const size_t brow = (size_t)srow * K + skc * 8;

#define LOADG(k0)                                                  \
    ra0 = *(const uint4*)(A + arow + (k0));                        \
    ra1 = *(const uint4*)(A + arow + (size_t)64 * K + (k0));       \
    rb0 = *(const uint4*)(BT + brow + (k0));
#define WRITEL(buf)                                                \
    *(uint4*)&Ash[buf][srow][skc * 8] = ra0;                       \
    *(uint4*)&Ash[buf][srow + 64][skc * 8] = ra1;                  \
    *(uint4*)&Bsh[buf][srow][skc * 8] = rb0;

    LOADG(0)
    WRITEL(0)
    __syncthreads();

    int cur = 0;
    for (int k0 = 0; k0 < K; k0 += 32) {
        const bool pf = (k0 + 32 < K);
        if (pf) { LOADG(k0 + 32) }
        half8 af[4], bf[2];
#pragma unroll
        for (int m = 0; m < 4; m++)
            af[m] = *(const half8*)&Ash[cur][wr * 64 + m * 16 + l15][lk * 8];
#pragma unroll
        for (int n = 0; n < 2; n++)
            bf[n] = *(const half8*)&Bsh[cur][wc * 32 + n * 16 + l15][lk * 8];
#pragma unroll
        for (int m = 0; m < 4; m++)
#pragma unroll
            for (int n = 0; n < 2; n++)
                acc[m][n] = __builtin_amdgcn_mfma_f32_16x16x32_f16(af[m], bf[n], acc[m][n], 0, 0, 0);
        if (pf) { WRITEL(cur ^ 1) }
        __syncthreads();
        cur ^= 1;
    }
#undef LOADG
#undef WRITEL

#pragma unroll
    for (int m = 0; m < 4; m++) {
#pragma unroll
        for (int n = 0; n < 2; n++) {
            int col = colbase + wc * 32 + n * 16 + l15;
#pragma unroll
            for (int r = 0; r < 4; r++) {
                int row = bm + wr * 64 + m * 16 + lk * 4 + r;
                float c = acc[m][n][r];
                if (bx == 0) c = tanhf(c);
                else if (bx >= 2) c = sigf(c);
                h1[(size_t)row * 256 + col] = f2h(c);
            }
        }
    }
}

// ===========================================================================
// low-rank stage 2: grid (16,16,3).
// z=0: exp(-exp(w0 + h1[:,0:64]@w2)) -> pack SL_W
// z=1: sigmoid(a0 + h1[:,64:128]@a2) -> pack SL_BV
// z=2: h1[:,128:256]@g2 -> gbuf (f32)
// ===========================================================================
__global__ __launch_bounds__(256) void lr2_k(
    const unsigned short* __restrict__ h1, const unsigned short* __restrict__ wts,
    const float* __restrict__ w0, const float* __restrict__ a0,
    float* __restrict__ pack, float* __restrict__ gbuf)
{
    __shared__ unsigned short Ash[128][40];
    __shared__ unsigned short Bsh[64][40];
    const int z = blockIdx.z;
    const int K = (z == 2) ? 128 : 64;
    const int aoff = (z == 0) ? 0 : (z == 1) ? 64 : 128;
    const unsigned short* BT = wts + 262144 + z * 65536;
    const int tid = threadIdx.x;
    const int lane = tid & 63, wid = tid >> 6;
    const int wr = wid >> 1, wc = wid & 1;
    const int bm = blockIdx.y * 128, bn = blockIdx.x * 64;
    const int l15 = lane & 15, lk = lane >> 4;
    const int srow = tid >> 2, skc = tid & 3;

    f32x4 acc[4][2];
#pragma unroll
    for (int i = 0; i < 4; i++)
#pragma unroll
        for (int j = 0; j < 2; j++) acc[i][j] = (f32x4){0.f, 0.f, 0.f, 0.f};

    for (int k0 = 0; k0 < K; k0 += 32) {
        uint4 ra0 = *(const uint4*)(h1 + (size_t)(bm + srow) * 256 + aoff + k0 + skc * 8);
        uint4 ra1 = *(const uint4*)(h1 + (size_t)(bm + srow + 64) * 256 + aoff + k0 + skc * 8);
        uint4 rb0 = *(const uint4*)(BT + (size_t)(bn + srow) * K + k0 + skc * 8);
        *(uint4*)&Ash[srow][skc * 8] = ra0;
        *(uint4*)&Ash[srow + 64][skc * 8] = ra1;
        *(uint4*)&Bsh[srow][skc * 8] = rb0;
        __syncthreads();
        half8 af[4], bf[2];
#pragma unroll
        for (int m = 0; m < 4; m++)
            af[m] = *(const half8*)&Ash[wr * 64 + m * 16 + l15][lk * 8];
#pragma unroll
        for (int n = 0; n < 2; n++)
            bf[n] = *(const half8*)&Bsh[wc * 32 + n * 16 + l15][lk * 8];
#pragma unroll
        for (int m = 0; m < 4; m++)
#pragma unroll
            for (int n = 0; n < 2; n++)
                acc[m][n] = __builtin_amdgcn_mfma_f32_16x16x32_f16(af[m], bf[n], acc[m][n], 0, 0, 0);
        __syncthreads();
    }

#pragma unroll
    for (int m = 0; m < 4; m++) {
#pragma unroll
        for (int n = 0; n < 2; n++) {
            int col = bn + wc * 32 + n * 16 + l15;
#pragma unroll
            for (int r = 0; r < 4; r++) {
                int row = bm + wr * 64 + m * 16 + lk * 4 + r;
                float c = acc[m][n][r];
                int b = row >> 10, t = row & (Tt - 1);
                int h = col >> 6, nn2 = col & 63;
                if (z == 0) {
                    pack[((size_t)(b * Hh + h) * Tt + t) * PACKW + SL_W * Nn + nn2] = expf(-expf(w0[col] + c));
                } else if (z == 1) {
                    pack[((size_t)(b * Hh + h) * Tt + t) * PACKW + SL_BV * Nn + nn2] = sigf(a0[col] + c);
                } else {
                    gbuf[(size_t)row * Cc + col] = c;
                }
            }
        }
    }
}

// ===========================================================================
// prep: kk normalize etc
// ===========================================================================
__global__ __launch_bounds__(256) void prep_k(float* __restrict__ pk,
                                              const float* __restrict__ k_k,
                                              const float* __restrict__ k_a)
{
    int inst = blockIdx.x * 4 + (threadIdx.x >> 6);
    int lane = threadIdx.x & 63;
    int b = inst >> 14;
    int rem = inst & 16383;
    int t = rem >> 4;
    int h = rem & 15;
    size_t base = ((size_t)(b * Hh + h) * Tt + t) * PACKW;
    int c = h * 64 + lane;
    float kraw = pk[base + SL_K * 64 + lane];
    float a = pk[base + SL_BV * 64 + lane];
    float kkv = kraw * k_k[c];
    float ss = kkv * kkv;
#pragma unroll
    for (int m = 1; m < 64; m <<= 1) ss += __shfl_xor(ss, m);
    float kkn = kkv / fmaxf(sqrtf(ss), 1e-12f);
    pk[base + SL_NK * 64 + lane] = -kkn;
    pk[base + SL_BV * 64 + lane] = kkn * a;
    pk[base + SL_K * 64 + lane] = kraw * (1.f + (a - 1.f) * k_a[c]);
}

// ===========================================================================
// WKV scan v6: 512 one-wave blocks, 4 rows/wave, 8-deep ASM register ring
// (volatile global_load_dwordx4 + counted vmcnt + sched_barrier), DPP red16.
// Known-good configuration: 129 us (R6 measurement).
// ===========================================================================
template <int C>
__device__ __forceinline__ float dppmov(float x) {
    return __int_as_float(__builtin_amdgcn_mov_dpp(__float_as_int(x), C, 0xF, 0xF, 1));
}
__device__ __forceinline__ float red16(float v) {
    v += dppmov<0xB1>(v);   // quad_perm xor1
    v += dppmov<0x4E>(v);   // quad_perm xor2
    v += dppmov<0x141>(v);  // row_half_mirror
    v += dppmov<0x140>(v);  // row_mirror
    return v;
}

struct Slot { f32x4 r, w, k, n, b; float v; };

__device__ __forceinline__ void stepf6(f32x4& S, const Slot& f, int jb, float* optr)
{
    float sa = fmaf(S[3], f.n[3], fmaf(S[2], f.n[2], fmaf(S[1], f.n[1], S[0] * f.n[0])));
    sa = red16(sa);
    S[0] = fmaf(S[0], f.w[0], fmaf(sa, f.b[0], f.v * f.k[0]));
    S[1] = fmaf(S[1], f.w[1], fmaf(sa, f.b[1], f.v * f.k[1]));
    S[2] = fmaf(S[2], f.w[2], fmaf(sa, f.b[2], f.v * f.k[2]));
    S[3] = fmaf(S[3], f.w[3], fmaf(sa, f.b[3], f.v * f.k[3]));
    float ot = fmaf(S[3], f.r[3], fmaf(S[2], f.r[2], fmaf(S[1], f.r[1], S[0] * f.r[0])));
    ot = red16(ot);
    if (jb == 0) *optr = ot;
}

__global__ __launch_bounds__(64, 1) void wkv_k(const float* __restrict__ pk, float* __restrict__ o)
{
    const int bx = blockIdx.x;          // 0..511
    const int xcd = bx & 7;
    const int ix = bx >> 3;             // 0..63
    const int bh = ((ix >> 4) << 3) | xcd;
    const int rg = ix & 15;
    const int lane = threadIdx.x;
    const int ri = lane >> 4, jb = lane & 15, j0 = jb * 4;
    const int i = rg * 4 + ri;
    const int b = bh >> 4, h = bh & 15;
    const float* pb = pk + (size_t)bh * Tt * PACKW;
    float* ob = o + (size_t)b * Tt * Cc + h * 64 + i;

    Slot sl[8];
    const float* p1 = pb + j0;
    const float* p2 = pb + SL_V * 64 + i;

    // offsets within a step (bytes): r=0, w=256, k=512, nk=1024, bv=1280
#define ISSUE(s, q1v, q2v)                                                                                \
    asm volatile("global_load_dwordx4 %0, %1, off"             : "=v"(sl[s].r) : "v"(q1v) : "memory");    \
    asm volatile("global_load_dwordx4 %0, %1, off offset:256"  : "=v"(sl[s].w) : "v"(q1v) : "memory");    \
    asm volatile("global_load_dwordx4 %0, %1, off offset:512"  : "=v"(sl[s].k) : "v"(q1v) : "memory");    \
    asm volatile("global_load_dwordx4 %0, %1, off offset:1024" : "=v"(sl[s].n) : "v"(q1v) : "memory");    \
    asm volatile("global_load_dwordx4 %0, %1, off offset:1280" : "=v"(sl[s].b) : "v"(q1v) : "memory");    \
    asm volatile("global_load_dword %0, %1, off"               : "=v"(sl[s].v) : "v"(q2v) : "memory");

    // prologue: slots 0..7 <- steps 0..7  (48 loads in flight)
    ISSUE(0, p1 + 0 * PACKW, p2 + 0 * PACKW)
    ISSUE(1, p1 + 1 * PACKW, p2 + 1 * PACKW)
    ISSUE(2, p1 + 2 * PACKW, p2 + 2 * PACKW)
    ISSUE(3, p1 + 3 * PACKW, p2 + 3 * PACKW)
    ISSUE(4, p1 + 4 * PACKW, p2 + 4 * PACKW)
    ISSUE(5, p1 + 5 * PACKW, p2 + 5 * PACKW)
    ISSUE(6, p1 + 6 * PACKW, p2 + 6 * PACKW)
    ISSUE(7, p1 + 7 * PACKW, p2 + 7 * PACKW)

    const float* q1 = p1 + 8 * PACKW;
    const float* q2 = p2 + 8 * PACKW;
    f32x4 S = (f32x4){0.f, 0.f, 0.f, 0.f};

#define STEP(u)                                                          \
    asm volatile("s_waitcnt vmcnt(42)" ::: "memory");                    \
    __builtin_amdgcn_sched_barrier(0);                                   \
    stepf6(S, sl[u], jb, ob + (size_t)(t0 + (u)) * Cc);                  \
    ISSUE(u, q1, q2)                                                     \
    if (t0 + (u) + 9 < Tt) { q1 += PACKW; q2 += PACKW; }

    for (int t0 = 0; t0 < Tt; t0 += 8) {
        STEP(0) STEP(1) STEP(2) STEP(3) STEP(4) STEP(5) STEP(6) STEP(7)
    }
#undef STEP
#undef ISSUE
}

// ===========================================================================
// post: GroupNorm + rkv + rosa gate + *g -> f16 activation
// ===========================================================================
__global__ __launch_bounds__(256) void post_k(
    const float* __restrict__ o, const float* __restrict__ pk, const float* __restrict__ gbuf,
    const float* __restrict__ r_k, const float* __restrict__ ln_w, const float* __restrict__ ln_b,
    const int* __restrict__ ids, const float* __restrict__ emb, const float* __restrict__ rgate,
    unsigned short* __restrict__ outh)
{
    __shared__ float sred[4];
    const int bt = blockIdx.x;
    const int b = bt >> 10, t = bt & 1023;
    const int tid = threadIdx.x;
    const int c0 = tid * 4;
    const int h = tid >> 4;
    const int nn = c0 & 63;

    float4 o4 = *(const float4*)(o + (size_t)bt * Cc + c0);
    float s = o4.x + o4.y + o4.z + o4.w;
    float ss = o4.x * o4.x + o4.y * o4.y + o4.z * o4.z + o4.w * o4.w;
#pragma unroll
    for (int m = 1; m < 16; m <<= 1) { s += __shfl_xor(s, m); ss += __shfl_xor(ss, m); }
    float mu = s * (1.f / 64.f);
    float inv = rsqrtf(ss * (1.f / 64.f) - mu * mu + 0.00064f);

    size_t pbase = ((size_t)(b * Hh + h) * Tt + t) * PACKW;
    float4 r4 = *(const float4*)(pk + pbase + SL_R * 64 + nn);
    float4 k4 = *(const float4*)(pk + pbase + SL_K * 64 + nn);
    float4 v4 = *(const float4*)(pk + pbase + SL_V * 64 + nn);
    float4 q4 = *(const float4*)(r_k + h * 64 + nn);
    float dot = r4.x * k4.x * q4.x + r4.y * k4.y * q4.y + r4.z * k4.z * q4.z + r4.w * k4.w * q4.w;
#pragma unroll
    for (int m = 1; m < 16; m <<= 1) dot += __shfl_xor(dot, m);

    float4 lw = *(const float4*)(ln_w + c0);
    float4 lb = *(const float4*)(ln_b + c0);
    float e0 = (o4.x - mu) * inv * lw.x + lb.x + dot * v4.x;
    float e1 = (o4.y - mu) * inv * lw.y + lb.y + dot * v4.y;
    float e2 = (o4.z - mu) * inv * lw.z + lb.z + dot * v4.z;
    float e3 = (o4.w - mu) * inv * lw.w + lb.w + dot * v4.w;

    float4 rg4 = *(const float4*)(rgate + c0);
    float gp = sigf(e0 * rg4.x) + sigf(e1 * rg4.y) + sigf(e2 * rg4.z) + sigf(e3 * rg4.w);
#pragma unroll
    for (int m = 1; m < 64; m <<= 1) gp += __shfl_xor(gp, m);
    if ((tid & 63) == 0) sred[tid >> 6] = gp;
    __syncthreads();
    float gate = (sred[0] + sred[1] + sred[2] + sred[3]) * (1.f / 1024.f);

    const int id = ids[bt];
    float4 em = *(const float4*)(emb + (size_t)id * Cc + c0);
    float4 g4 = *(const float4*)(gbuf + (size_t)bt * Cc + c0);
    ushort4 h4;
    h4.x = f2h((e0 * (1.f - gate) + em.x * gate) * g4.x);
    h4.y = f2h((e1 * (1.f - gate) + em.y * gate) * g4.y);
    h4.z = f2h((e2 * (1.f - gate) + em.z * gate) * g4.z);
    h4.w = f2h((e3 * (1.f - gate) + em.w * gate) * g4.w);
    *(ushort4*)(outh + (size_t)bt * Cc + c0) = h4;
}

// ===========================================================================
extern "C" void kernel_launch(void* const* d_in, const int* in_sizes, int n_in,
                              void* d_out, int out_size, void* d_ws, size_t ws_size,
                              hipStream_t stream)
{
    (void)in_sizes; (void)n_in; (void)out_size; (void)ws_size;
    const float* x    = (const float*)d_in[0];
    const int*   ids  = (const int*)d_in[1];
    const float* x_r  = (const float*)d_in[2];
    const float* x_w  = (const float*)d_in[3];
    const float* x_k  = (const float*)d_in[4];
    const float* x_v  = (const float*)d_in[5];
    const float* x_a  = (const float*)d_in[6];
    const float* x_g  = (const float*)d_in[7];
    const float* w0   = (const float*)d_in[8];
    const float* a0   = (const float*)d_in[9];
    const float* w1   = (const float*)d_in[11];
    const float* w2   = (const float*)d_in[12];
    const float* a1   = (const float*)d_in[13];
    const float* a2   = (const float*)d_in[14];
    const float* g1   = (const float*)d_in[17];
    const float* g2   = (const float*)d_in[18];
    const float* k_k  = (const float*)d_in[19];
    const float* k_a  = (const float*)d_in[20];
    const float* r_k  = (const float*)d_in[21];
    const float* Wr   = (const float*)d_in[22];
    const float* Wk   = (const float*)d_in[23];
    const float* Wv   = (const float*)d_in[24];
    const float* Wo   = (const float*)d_in[25];
    const float* ln_w = (const float*)d_in[26];
    const float* ln_b = (const float*)d_in[27];
    const float* emb  = (const float*)d_in[28];
    const float* rg   = (const float*)d_in[29];

    float* ws = (float*)d_ws;
    float* pack = ws;                                          // 12,582,912 f
    float* obuf = pack + (size_t)12582912;                     // 2,097,152 f
    float* gbuf = obuf + (size_t)2097152;                      // 2,097,152 f
    unsigned short* xf  = (unsigned short*)(gbuf + (size_t)2097152);  // 6 x 2,097,152 u16
    unsigned short* wt  = xf + (size_t)6 * 2097152;            // 4 x 1,048,576 u16
    unsigned short* wts = wt + (size_t)4 * 1048576;            // 524,288 u16
    unsigned short* h1  = wts + (size_t)524288;                // 524,288 u16
    unsigned short* obh = xf;   // final activation aliases xr (dead after R proj)

    dim3 blk(256);

    wtrans_k<<<dim3(16, 16, 4), blk, 0, stream>>>(Wr, Wk, Wv, Wo, wt);
    tr6_k<<<dim3(128), blk, 0, stream>>>(w1, a1, g1, w2, a2, g2, wts);
    mixcast_k<<<dim3(2048), blk, 0, stream>>>(x, x_r, x_k, x_v, x_w, x_a, x_g, xf);

    // r, k, v projections (merged z) -> pack slots
    mgemm_k<1><<<dim3(Cc / 64, Mtot / 128, 3), blk, 0, stream>>>(xf, wt, pack, Mtot, Cc, Cc);
    // low-rank chains
    lr1_k<<<dim3(4, 16), blk, 0, stream>>>(xf, wts, h1);
    lr2_k<<<dim3(16, 16, 3), blk, 0, stream>>>(h1, wts, w0, a0, pack, gbuf);

    prep_k<<<dim3(Bb * Tt * Hh / 4), blk, 0, stream>>>(pack, k_k, k_a);
    wkv_k<<<dim3(512), dim3(64), 0, stream>>>(pack, obuf);
    post_k<<<dim3(Mtot), blk, 0, stream>>>(obuf, pack, gbuf, r_k, ln_w, ln_b, ids, emb, rg, obh);
    mgemm_k<0><<<dim3(Cc / 64, Mtot / 128, 1), blk, 0, stream>>>(obh, wt + (size_t)3 * 1048576, (float*)d_out, Mtot, Cc, Cc);
}